// Round 3
// baseline (2058.191 us; speedup 1.0000x reference)
//
#include <hip/hip_runtime.h>
#include <math.h>

#define BB 8
#define CC 512
#define TT 2048
#define ICC 256
#define EPSV 1e-5f

// ---------------------------------------------------------------------------
// Generic fp32 tiled GEMM: Out[b,m,t] = sum_c W[m,c] * X[b,c,t] + bias[m]
// grid (TT/64, M/64, BB), block 256. Optionally accumulates per-channel
// sum / sumsq (DOUBLE precision) for BatchNorm via atomics.
// ---------------------------------------------------------------------------
template <int M, int K, bool STATS>
__global__ __launch_bounds__(256) void gemm_proj(
    const float* __restrict__ W, const float* __restrict__ bias,
    const float* __restrict__ X, float* __restrict__ Out,
    double* __restrict__ osum, double* __restrict__ osumsq) {
  __shared__ float Ws[16][65];  // Ws[k][m]
  __shared__ float Xs[16][65];  // Xs[k][t]
  const int bt = blockIdx.x * 64;
  const int bm = blockIdx.y * 64;
  const int b = blockIdx.z;
  const int tid = threadIdx.x;
  const int tx = tid & 15, ty = tid >> 4;
  const float* Xb = X + (size_t)b * K * TT;
  float acc[4][4] = {};
  for (int kb = 0; kb < K; kb += 16) {
#pragma unroll
    for (int r = 0; r < 4; ++r) {
      int idx = tid + r * 256;  // 0..1023
      int m = idx >> 4, k = idx & 15;
      Ws[k][m] = W[(size_t)(bm + m) * K + kb + k];
      int kx = idx >> 6, t = idx & 63;
      Xs[kx][t] = Xb[(size_t)(kb + kx) * TT + bt + t];
    }
    __syncthreads();
#pragma unroll
    for (int k = 0; k < 16; ++k) {
      float a[4], bv[4];
#pragma unroll
      for (int i = 0; i < 4; ++i) a[i] = Ws[k][ty * 4 + i];
#pragma unroll
      for (int j = 0; j < 4; ++j) bv[j] = Xs[k][tx * 4 + j];
#pragma unroll
      for (int i = 0; i < 4; ++i)
#pragma unroll
        for (int j = 0; j < 4; ++j) acc[i][j] += a[i] * bv[j];
    }
    __syncthreads();
  }
#pragma unroll
  for (int i = 0; i < 4; ++i) {
    int m = bm + ty * 4 + i;
    float bv = bias[m];
    double rs = 0.0, rq = 0.0;
#pragma unroll
    for (int j = 0; j < 4; ++j) {
      float v = acc[i][j] + bv;
      Out[((size_t)b * M + m) * TT + bt + tx * 4 + j] = v;
      if (STATS) {
        rs += (double)v;
        rq += (double)v * (double)v;
      }
    }
    if (STATS) {
#pragma unroll
      for (int s = 8; s >= 1; s >>= 1) {
        rs += __shfl_xor(rs, s, 16);
        rq += __shfl_xor(rq, s, 16);
      }
      if (tx == 0) {
        atomicAdd(&osum[m], rs);
        atomicAdd(&osumsq[m], rq);
      }
    }
  }
}

// ---------------------------------------------------------------------------
// Flash-style fused attention (fp32):
//   S[i,j] = sum_c th[b,c,i0+i] * ph[b,c,j]  (online softmax over j)
//   y[b,c,i0+i] = sum_j softmax(S)[i,j] * g[b,c,j]
// grid (TT/64, BB), block 256.  64-query tile per block, 64-key chunks.
// NOTE: y may alias th (block reads th only at its own i-range, writes at end).
// ---------------------------------------------------------------------------
__global__ __launch_bounds__(256) void attn_flash(
    const float* __restrict__ th, const float* __restrict__ ph,
    const float* __restrict__ gx, float* __restrict__ y) {
  __shared__ float As[16][65];  // theta chunk [k][i]
  __shared__ float Bs[16][65];  // phi chunk   [k][j]
  __shared__ float Ps[64][65];  // p[i][j]
  __shared__ float Gs[64][65];  // g chunk [c'][j]
  __shared__ float mScale[64];
  __shared__ float lArr[64];
  const int i0 = blockIdx.x * 64;
  const int b = blockIdx.y;
  const int tid = threadIdx.x;
  const int tx = tid & 15, ty = tid >> 4;
  const float* thb = th + (size_t)b * ICC * TT;
  const float* phb = ph + (size_t)b * ICC * TT;
  const float* gb = gx + (size_t)b * ICC * TT;
  float m[4], l[4];
#pragma unroll
  for (int i = 0; i < 4; ++i) {
    m[i] = -1e30f;
    l[i] = 0.f;
  }
  float acc[4][4][4] = {};  // [cq][ci][jq]  (c = cq*64+ty*4+ci, q = tx*4+jq)

  for (int j0 = 0; j0 < TT; j0 += 64) {
    // ---- S = theta^T phi over this key chunk
    float S[4][4] = {};
    for (int cb = 0; cb < ICC; cb += 16) {
#pragma unroll
      for (int r = 0; r < 4; ++r) {
        int idx = tid + r * 256;
        int k = idx >> 6, col = idx & 63;
        As[k][col] = thb[(size_t)(cb + k) * TT + i0 + col];
        Bs[k][col] = phb[(size_t)(cb + k) * TT + j0 + col];
      }
      __syncthreads();
#pragma unroll
      for (int k = 0; k < 16; ++k) {
        float a[4], bv[4];
#pragma unroll
        for (int i = 0; i < 4; ++i) a[i] = As[k][ty * 4 + i];
#pragma unroll
        for (int j = 0; j < 4; ++j) bv[j] = Bs[k][tx * 4 + j];
#pragma unroll
        for (int i = 0; i < 4; ++i)
#pragma unroll
          for (int j = 0; j < 4; ++j) S[i][j] += a[i] * bv[j];
      }
      __syncthreads();
    }
    // ---- online softmax update, rows q = ty*4+i owned across the 16 tx lanes
    float sc[4];
#pragma unroll
    for (int i = 0; i < 4; ++i) {
      float mc = S[i][0];
#pragma unroll
      for (int j = 1; j < 4; ++j) mc = fmaxf(mc, S[i][j]);
#pragma unroll
      for (int s = 8; s >= 1; s >>= 1) mc = fmaxf(mc, __shfl_xor(mc, s, 16));
      float mn = fmaxf(m[i], mc);
      sc[i] = __expf(m[i] - mn);
      float lsum = 0.f;
#pragma unroll
      for (int j = 0; j < 4; ++j) {
        float p = __expf(S[i][j] - mn);
        S[i][j] = p;
        lsum += p;
      }
#pragma unroll
      for (int s = 8; s >= 1; s >>= 1) lsum += __shfl_xor(lsum, s, 16);
      l[i] = l[i] * sc[i] + lsum;
      m[i] = mn;
#pragma unroll
      for (int j = 0; j < 4; ++j) Ps[ty * 4 + i][tx * 4 + j] = S[i][j];
    }
    if (tx == 0) {
#pragma unroll
      for (int i = 0; i < 4; ++i) mScale[ty * 4 + i] = sc[i];
    }
    __syncthreads();
    // ---- PV: acc[c,q] += sum_j g[c,j] * p[q,j], per 64-channel quadrant
#pragma unroll
    for (int cq = 0; cq < 4; ++cq) {
      // stage FULL 64x64 g tile: 4096 elements = 16 iters x 256 threads
#pragma unroll
      for (int r = 0; r < 16; ++r) {
        int idx = tid + r * 256;  // 0..4095
        int cpr = idx >> 6, j = idx & 63;
        Gs[cpr][j] = gb[(size_t)(cq * 64 + cpr) * TT + j0 + j];
      }
      __syncthreads();
      float scj[4];
#pragma unroll
      for (int jq = 0; jq < 4; ++jq) scj[jq] = mScale[tx * 4 + jq];
#pragma unroll
      for (int ci = 0; ci < 4; ++ci)
#pragma unroll
        for (int jq = 0; jq < 4; ++jq) acc[cq][ci][jq] *= scj[jq];
      for (int j = 0; j < 64; ++j) {
        float a[4], p[4];
#pragma unroll
        for (int ci = 0; ci < 4; ++ci) a[ci] = Gs[ty * 4 + ci][j];
#pragma unroll
        for (int jq = 0; jq < 4; ++jq) p[jq] = Ps[tx * 4 + jq][j];
#pragma unroll
        for (int ci = 0; ci < 4; ++ci)
#pragma unroll
          for (int jq = 0; jq < 4; ++jq) acc[cq][ci][jq] += a[ci] * p[jq];
      }
      __syncthreads();
    }
  }
  // ---- finalize: y = acc / l
  if (tx == 0) {
#pragma unroll
    for (int i = 0; i < 4; ++i) lArr[ty * 4 + i] = l[i];
  }
  __syncthreads();
  float linv[4];
#pragma unroll
  for (int jq = 0; jq < 4; ++jq) linv[jq] = 1.f / lArr[tx * 4 + jq];
#pragma unroll
  for (int cq = 0; cq < 4; ++cq)
#pragma unroll
    for (int ci = 0; ci < 4; ++ci)
#pragma unroll
      for (int jq = 0; jq < 4; ++jq)
        y[((size_t)b * ICC + cq * 64 + ty * 4 + ci) * TT + i0 + tx * 4 + jq] =
            acc[cq][ci][jq] * linv[jq];
}

// ---------------------------------------------------------------------------
__global__ void zero_stats(double* s) {
  s[threadIdx.x] = 0.0;  // 1024 doubles: [0..511]=sum, [512..1023]=sumsq
}

__global__ void bn_stats(const double* __restrict__ osum,
                         const double* __restrict__ osumsq,
                         float* __restrict__ mean, float* __restrict__ rstd) {
  int o = threadIdx.x;
  if (o < CC) {
    const double inv = 1.0 / (double)(BB * TT);
    double mu = osum[o] * inv;
    double var = osumsq[o] * inv - mu * mu;
    mean[o] = (float)mu;
    rstd[o] = (float)(1.0 / sqrt(var + (double)EPSV));
  }
}

// out = relu((wy - mean) * rstd * gamma + beta) + x   (in-place on d_out)
__global__ __launch_bounds__(256) void bn_apply(
    float* __restrict__ out, const float* __restrict__ x,
    const float* __restrict__ mean, const float* __restrict__ rstd,
    const float* __restrict__ gamma, const float* __restrict__ beta) {
  const size_t n4 = (size_t)BB * CC * TT / 4;
  for (size_t idx = (size_t)blockIdx.x * blockDim.x + threadIdx.x; idx < n4;
       idx += (size_t)gridDim.x * blockDim.x) {
    size_t e = idx * 4;
    int o = (int)((e / TT) % CC);
    float4 wv = ((const float4*)out)[idx];
    float4 xv = ((const float4*)x)[idx];
    float mu = mean[o], rs = rstd[o], ga = gamma[o], be = beta[o];
    float4 r;
    r.x = fmaxf((wv.x - mu) * rs * ga + be, 0.f) + xv.x;
    r.y = fmaxf((wv.y - mu) * rs * ga + be, 0.f) + xv.y;
    r.z = fmaxf((wv.z - mu) * rs * ga + be, 0.f) + xv.z;
    r.w = fmaxf((wv.w - mu) * rs * ga + be, 0.f) + xv.w;
    ((float4*)out)[idx] = r;
  }
}

// ---------------------------------------------------------------------------
extern "C" void kernel_launch(void* const* d_in, const int* in_sizes, int n_in,
                              void* d_out, int out_size, void* d_ws,
                              size_t ws_size, hipStream_t stream) {
  const float* x = (const float*)d_in[0];
  const float* g_w = (const float*)d_in[1];
  const float* g_b = (const float*)d_in[2];
  const float* th_w = (const float*)d_in[3];
  const float* th_b = (const float*)d_in[4];
  const float* ph_w = (const float*)d_in[5];
  const float* ph_b = (const float*)d_in[6];
  const float* W_w = (const float*)d_in[7];
  const float* W_b = (const float*)d_in[8];
  const float* gamma = (const float*)d_in[9];
  const float* beta = (const float*)d_in[10];
  float* out = (float*)d_out;
  float* ws = (float*)d_ws;

  const size_t np = (size_t)BB * ICC * TT;  // 4.19M floats per (B,IC,T) buffer
  float* thb = ws;            // theta  (B,IC,T)
  float* phb = ws + np;       // phi    (B,IC,T)
  float* gbuf = ws + 2 * np;  // g      (B,IC,T)
  float* yb = thb;            // y aliases theta (safe: see attn_flash note)
  double* statd = (double*)(ws + 3 * np);  // 1024 doubles (8-aligned: 3*np*4 bytes)
  float* meanb = (float*)(statd + 1024);   // 512 floats
  float* rstdb = meanb + 512;              // 512 floats

  dim3 blk(256);
  // 1) projections: theta, phi, g
  gemm_proj<ICC, CC, false><<<dim3(TT / 64, ICC / 64, BB), blk, 0, stream>>>(
      th_w, th_b, x, thb, nullptr, nullptr);
  gemm_proj<ICC, CC, false><<<dim3(TT / 64, ICC / 64, BB), blk, 0, stream>>>(
      ph_w, ph_b, x, phb, nullptr, nullptr);
  gemm_proj<ICC, CC, false><<<dim3(TT / 64, ICC / 64, BB), blk, 0, stream>>>(
      g_w, g_b, x, gbuf, nullptr, nullptr);
  // 2) fused attention -> y
  attn_flash<<<dim3(TT / 64, BB), blk, 0, stream>>>(thb, phb, gbuf, yb);
  // 3) W conv -> d_out (wy), + BN stats (double atomics)
  zero_stats<<<1, 1024, 0, stream>>>(statd);
  gemm_proj<CC, ICC, true><<<dim3(TT / 64, CC / 64, BB), blk, 0, stream>>>(
      W_w, W_b, yb, out, statd, statd + CC);
  // 4) finalize mean/rstd (double -> float)
  bn_stats<<<1, 512, 0, stream>>>(statd, statd + CC, meanb, rstdb);
  // 5) BN + ReLU + residual, in place on d_out
  bn_apply<<<2048, 256, 0, stream>>>(out, x, meanb, rstdb, gamma, beta);
}

// Round 6
// 536.540 us; speedup vs baseline: 3.8360x; 3.8360x over previous
//
#include <hip/hip_runtime.h>
#include <math.h>

#define BB 8
#define CC 512
#define TT 2048
#define ICC 256
#define EPSV 1e-5f
#define SC2048 2048.0f
#define INV2048 4.8828125e-4f

typedef _Float16 f16;
typedef __attribute__((ext_vector_type(8))) _Float16 f16x8;
typedef __attribute__((ext_vector_type(4))) float f32x4;

#define MFMA(a, b, c) __builtin_amdgcn_mfma_f32_16x16x32_f16(a, b, c, 0, 0, 0)

__device__ __forceinline__ int swz(int byte, int row) {
  return byte ^ ((row & 7) << 4);
}

// ---------------------------------------------------------------------------
// P0: x[b][c][t] f32 -> xT hi / scaled-lo f16 [b][t][c]
// ---------------------------------------------------------------------------
__global__ __launch_bounds__(256) void split_transpose_x(
    const float* __restrict__ x, f16* __restrict__ xh, f16* __restrict__ xl) {
  __shared__ float tile[32][33];
  const int tx = threadIdx.x, ty = threadIdx.y;
  const int t0 = blockIdx.x * 32, c0 = blockIdx.y * 32, b = blockIdx.z;
#pragma unroll
  for (int k = 0; k < 4; ++k)
    tile[ty + 8 * k][tx] = x[((size_t)b * CC + c0 + ty + 8 * k) * TT + t0 + tx];
  __syncthreads();
#pragma unroll
  for (int k = 0; k < 4; ++k) {
    float v = tile[tx][ty + 8 * k];
    size_t o = ((size_t)b * TT + t0 + ty + 8 * k) * CC + c0 + tx;
    f16 h = (f16)v;
    xh[o] = h;
    xl[o] = (f16)((v - (float)h) * SC2048);
  }
}

__global__ void split_w(const float* __restrict__ src, f16* __restrict__ h,
                        f16* __restrict__ lo, int n) {
  int i = blockIdx.x * 256 + threadIdx.x;
  if (i < n) {
    float v = src[i];
    f16 a = (f16)v;
    h[i] = a;
    lo[i] = (f16)((v - (float)a) * SC2048);
  }
}

// ---------------------------------------------------------------------------
// NT GEMM: D[M][N] = A[M][K] * B[N][K]^T + bias.  fp16 split with SCALED lo
// (lo' = (v-hi)*2048) and separate correction accumulator:
//   D = acc(hi*hi) + accL(lo'*hi + hi*lo') / 2048
// Block 128x128x(K-step 32), 4 waves each 64x64. grid (N/128, M/128, batch).
// ---------------------------------------------------------------------------
template <int M, int N, int K, bool BIAS_N, bool F32OUT>
__global__ __launch_bounds__(256) void gemm_nt(
    const f16* __restrict__ Ah, const f16* __restrict__ Al, long strideA,
    const f16* __restrict__ Bh, const f16* __restrict__ Bl, long strideB,
    const float* __restrict__ bias, f16* __restrict__ Oh, f16* __restrict__ Ol,
    float* __restrict__ Of, long strideO, double* __restrict__ osum,
    double* __restrict__ osumsq) {
  __shared__ f16 sAh[4096], sAl[4096], sBh[4096], sBl[4096];
  __shared__ float sOut[F32OUT ? 1 : 32 * 132];
  const int tid = threadIdx.x;
  const int w = tid >> 6, l = tid & 63;
  const int bn = blockIdx.x * 128, bm = blockIdx.y * 128;
  const size_t baseA = (size_t)blockIdx.z * strideA;
  const size_t baseB = (size_t)blockIdx.z * strideB;
  const size_t baseO = (size_t)blockIdx.z * strideO;
  const int m0 = (w >> 1) * 64, n0 = (w & 1) * 64;
  char* cAh = (char*)sAh;
  char* cAl = (char*)sAl;
  char* cBh = (char*)sBh;
  char* cBl = (char*)sBl;

  f32x4 acc[4][4], accL[4][4];
#pragma unroll
  for (int i = 0; i < 4; ++i)
#pragma unroll
    for (int j = 0; j < 4; ++j) {
      acc[i][j] = (f32x4){0.f, 0.f, 0.f, 0.f};
      accL[i][j] = (f32x4){0.f, 0.f, 0.f, 0.f};
    }

  for (int kb = 0; kb < K; kb += 32) {
    __syncthreads();
#pragma unroll
    for (int rep = 0; rep < 2; ++rep) {
      int slot = tid + rep * 256;  // 0..511
      int row = slot >> 2, ks = slot & 3;
      int byte = swz(row * 64 + ks * 16, row);
      size_t ga = baseA + (size_t)(bm + row) * K + kb + ks * 8;
      size_t gb = baseB + (size_t)(bn + row) * K + kb + ks * 8;
      *(f16x8*)(cAh + byte) = *(const f16x8*)(Ah + ga);
      *(f16x8*)(cAl + byte) = *(const f16x8*)(Al + ga);
      *(f16x8*)(cBh + byte) = *(const f16x8*)(Bh + gb);
      *(f16x8*)(cBl + byte) = *(const f16x8*)(Bl + gb);
    }
    __syncthreads();
    f16x8 ah[4], al[4];
#pragma unroll
    for (int mf = 0; mf < 4; ++mf) {
      int row = m0 + mf * 16 + (l & 15);
      int byte = swz(row * 64 + ((l >> 4) << 4), row);
      ah[mf] = *(const f16x8*)(cAh + byte);
      al[mf] = *(const f16x8*)(cAl + byte);
    }
#pragma unroll
    for (int nf = 0; nf < 4; ++nf) {
      int row = n0 + nf * 16 + (l & 15);
      int byte = swz(row * 64 + ((l >> 4) << 4), row);
      f16x8 bh = *(const f16x8*)(cBh + byte);
      f16x8 bl = *(const f16x8*)(cBl + byte);
#pragma unroll
      for (int mf = 0; mf < 4; ++mf)
        acc[mf][nf] = MFMA(ah[mf], bh, acc[mf][nf]);
#pragma unroll
      for (int mf = 0; mf < 4; ++mf)
        accL[mf][nf] = MFMA(al[mf], bh, accL[mf][nf]);
#pragma unroll
      for (int mf = 0; mf < 4; ++mf)
        accL[mf][nf] = MFMA(ah[mf], bl, accL[mf][nf]);
    }
  }

  if (F32OUT) {
#pragma unroll
    for (int mf = 0; mf < 4; ++mf)
#pragma unroll
      for (int r = 0; r < 4; ++r) {
        int mrow = bm + m0 + mf * 16 + ((l >> 4) << 2) + r;
        float bv = bias[mrow];
        double s = 0.0, q = 0.0;
#pragma unroll
        for (int nf = 0; nf < 4; ++nf) {
          float v = acc[mf][nf][r] + accL[mf][nf][r] * INV2048 + bv;
          Of[baseO + (size_t)mrow * N + bn + n0 + nf * 16 + (l & 15)] = v;
          s += (double)v;
          q += (double)v * (double)v;
        }
#pragma unroll
        for (int sh = 8; sh >= 1; sh >>= 1) {
          s += __shfl_xor(s, sh);
          q += __shfl_xor(q, sh);
        }
        if ((l & 15) == 0) {
          atomicAdd(&osum[mrow], s);
          atomicAdd(&osumsq[mrow], q);
        }
      }
  } else {
    // LDS transpose epilogue, 32-row chunks.  BUGFIX (r5->r6): rl must
    // include the wave's m0 offset; previously chunks c=2,3 indexed sOut
    // with NEGATIVE rows -> OOB LDS writes + stale data for rows 64..127.
    for (int c = 0; c < 4; ++c) {
      __syncthreads();
      if ((w >> 1) == (c >> 1)) {
#pragma unroll
        for (int mf2 = 0; mf2 < 2; ++mf2) {
          int mf = (c & 1) * 2 + mf2;
          int rl = m0 - c * 32 + mf * 16 + ((l >> 4) << 2);
#pragma unroll
          for (int nf = 0; nf < 4; ++nf)
#pragma unroll
            for (int r = 0; r < 4; ++r)
              sOut[(rl + r) * 132 + n0 + nf * 16 + (l & 15)] =
                  acc[mf][nf][r] + accL[mf][nf][r] * INV2048;
        }
      }
      __syncthreads();
      int row = tid >> 3, cc0 = (tid & 7) * 16;
      size_t gm = bm + c * 32 + row;
      size_t ob = baseO + gm * (size_t)N + bn + cc0;
      f16 hv[16], lv[16];
#pragma unroll
      for (int e = 0; e < 16; ++e) {
        float v = sOut[row * 132 + cc0 + e];
        v += BIAS_N ? bias[bn + cc0 + e] : bias[gm];
        f16 h = (f16)v;
        hv[e] = h;
        lv[e] = (f16)((v - (float)h) * SC2048);
      }
      *(f16x8*)&Oh[ob] = *(f16x8*)hv;
      *(f16x8*)&Oh[ob + 8] = *(f16x8*)(hv + 8);
      *(f16x8*)&Ol[ob] = *(f16x8*)lv;
      *(f16x8*)&Ol[ob + 8] = *(f16x8*)(lv + 8);
    }
  }
}

// ---------------------------------------------------------------------------
// Fused flash attention, fp16-split MFMA with scaled-lo correction passes.
// theta/phi: [b][t][256] hi/lo'.  g: [b][256][t] hi/lo'.  y out: [b][t][256].
// Block = 4 waves, 64 query rows, key chunks of 32.
// ---------------------------------------------------------------------------
__global__ __launch_bounds__(256) void attn_mfma(
    const f16* __restrict__ th_h, const f16* __restrict__ th_l,
    const f16* __restrict__ ph_h, const f16* __restrict__ ph_l,
    const f16* __restrict__ g_h, const f16* __restrict__ g_l,
    f16* __restrict__ y_h, f16* __restrict__ y_l) {
  __shared__ char U[33792];            // phi chunk <-> g chunk <-> f32 out
  __shared__ f16 sP[2048], sPl[2048];  // P hi / scaled-lo [64][32] swizzled
  __shared__ float sSc[64], sL[64];
  const int tid = threadIdx.x, w = tid >> 6, l = tid & 63;
  const int b = blockIdx.x & 7;
  const int i0 = (blockIdx.x >> 3) * 64;

  const size_t tbase =
      ((size_t)b * TT + i0 + w * 16 + (l & 15)) * 256 + ((l >> 4) << 3);
  f16x8 qh[8], ql[8];
#pragma unroll
  for (int kf = 0; kf < 8; ++kf) {
    qh[kf] = *(const f16x8*)(th_h + tbase + kf * 32);
    ql[kf] = *(const f16x8*)(th_l + tbase + kf * 32);
  }
  f32x4 yacc[4][4], yaccL[4][4];
#pragma unroll
  for (int i = 0; i < 4; ++i)
#pragma unroll
    for (int j = 0; j < 4; ++j) {
      yacc[i][j] = (f32x4){0.f, 0.f, 0.f, 0.f};
      yaccL[i][j] = (f32x4){0.f, 0.f, 0.f, 0.f};
    }
  float mrow[4], lrow[4];
#pragma unroll
  for (int r = 0; r < 4; ++r) {
    mrow[r] = -3e38f;
    lrow[r] = 0.f;
  }
  f16* Ph = (f16*)U;
  f16* Pl = Ph + 8192;  // phi: [32][256] hi, lo'
  f16* Gh = (f16*)U;
  f16* Gl = Gh + 8192;  // g:   [256][32] hi, lo' (time-shared with phi)

  for (int jc = 0; jc < 64; ++jc) {
    const int j0 = jc * 32;
    // ---- stage phi chunk [32 j][256 c]
#pragma unroll
    for (int rep = 0; rep < 4; ++rep) {
      int slot = tid + rep * 256;
      int row = slot >> 5, ks = slot & 31;
      int byte = swz(row * 512 + ks * 16, row);
      size_t ga = ((size_t)b * TT + j0 + row) * 256 + ks * 8;
      *(f16x8*)((char*)Ph + byte) = *(const f16x8*)(ph_h + ga);
      *(f16x8*)((char*)Pl + byte) = *(const f16x8*)(ph_l + ga);
    }
    __syncthreads();
    // ---- QK^T with correction accumulator
    f32x4 s4[2] = {(f32x4){0.f, 0.f, 0.f, 0.f}, (f32x4){0.f, 0.f, 0.f, 0.f}};
    f32x4 s4L[2] = {(f32x4){0.f, 0.f, 0.f, 0.f}, (f32x4){0.f, 0.f, 0.f, 0.f}};
#pragma unroll
    for (int kf = 0; kf < 8; ++kf) {
#pragma unroll
      for (int jf = 0; jf < 2; ++jf) {
        int row = jf * 16 + (l & 15);
        int byte = swz(row * 512 + kf * 64 + ((l >> 4) << 4), row);
        f16x8 bh = *(const f16x8*)((char*)Ph + byte);
        f16x8 bl = *(const f16x8*)((char*)Pl + byte);
        s4[jf] = MFMA(qh[kf], bh, s4[jf]);
        s4L[jf] = MFMA(ql[kf], bh, s4L[jf]);
        s4L[jf] = MFMA(qh[kf], bl, s4L[jf]);
      }
    }
    // ---- online softmax (rows il of wave's 16)
#pragma unroll
    for (int r = 0; r < 4; ++r) {
      float sv0 = s4[0][r] + s4L[0][r] * INV2048;
      float sv1 = s4[1][r] + s4L[1][r] * INV2048;
      float mx = fmaxf(sv0, sv1);
#pragma unroll
      for (int sh = 8; sh >= 1; sh >>= 1) mx = fmaxf(mx, __shfl_xor(mx, sh));
      float mn = fmaxf(mrow[r], mx);
      float sc = __expf(mrow[r] - mn);
      mrow[r] = mn;
      float p0 = __expf(sv0 - mn);
      float p1 = __expf(sv1 - mn);
      float ls = p0 + p1;
#pragma unroll
      for (int sh = 8; sh >= 1; sh >>= 1) ls += __shfl_xor(ls, sh);
      lrow[r] = lrow[r] * sc + ls;
      int il = w * 16 + ((l >> 4) << 2) + r;
      int jj0 = (l & 15), jj1 = 16 + (l & 15);
      f16 h0 = (f16)p0, h1 = (f16)p1;
      *(f16*)((char*)sP + swz(il * 64 + jj0 * 2, il)) = h0;
      *(f16*)((char*)sP + swz(il * 64 + jj1 * 2, il)) = h1;
      *(f16*)((char*)sPl + swz(il * 64 + jj0 * 2, il)) =
          (f16)((p0 - (float)h0) * SC2048);
      *(f16*)((char*)sPl + swz(il * 64 + jj1 * 2, il)) =
          (f16)((p1 - (float)h1) * SC2048);
      if ((l & 15) == 0) sSc[il] = sc;
    }
    __syncthreads();  // P + sSc published; phi reads done
    // ---- stage g chunk [256 c'][32 j]
#pragma unroll
    for (int rep = 0; rep < 4; ++rep) {
      int slot = tid + rep * 256;
      int row = slot >> 2, ks = slot & 3;
      int byte = swz(row * 64 + ks * 16, row);
      size_t ga = ((size_t)b * 256 + row) * TT + j0 + ks * 8;
      *(f16x8*)((char*)Gh + byte) = *(const f16x8*)(g_h + ga);
      *(f16x8*)((char*)Gl + byte) = *(const f16x8*)(g_l + ga);
    }
    __syncthreads();
    // ---- rescale yacc/yaccL
#pragma unroll
    for (int mf = 0; mf < 4; ++mf)
#pragma unroll
      for (int r = 0; r < 4; ++r) {
        float s0 = sSc[mf * 16 + ((l >> 4) << 2) + r];
#pragma unroll
        for (int cf = 0; cf < 4; ++cf) {
          yacc[mf][cf][r] *= s0;
          yaccL[mf][cf][r] *= s0;
        }
      }
    // ---- PV: A=P rows (all 64 i), B=g (wave's 64 c'), 3-pass split
#pragma unroll
    for (int mp = 0; mp < 2; ++mp) {
      f16x8 pa[2], paL[2];
#pragma unroll
      for (int mi = 0; mi < 2; ++mi) {
        int row = (mp * 2 + mi) * 16 + (l & 15);
        int byte = swz(row * 64 + ((l >> 4) << 4), row);
        pa[mi] = *(const f16x8*)((char*)sP + byte);
        paL[mi] = *(const f16x8*)((char*)sPl + byte);
      }
#pragma unroll
      for (int cf = 0; cf < 4; ++cf) {
        int crow = w * 64 + cf * 16 + (l & 15);
        int byte = swz(crow * 64 + ((l >> 4) << 4), crow);
        f16x8 gh = *(const f16x8*)((char*)Gh + byte);
        f16x8 gl = *(const f16x8*)((char*)Gl + byte);
#pragma unroll
        for (int mi = 0; mi < 2; ++mi)
          yacc[mp * 2 + mi][cf] = MFMA(pa[mi], gh, yacc[mp * 2 + mi][cf]);
#pragma unroll
        for (int mi = 0; mi < 2; ++mi)
          yaccL[mp * 2 + mi][cf] = MFMA(paL[mi], gh, yaccL[mp * 2 + mi][cf]);
#pragma unroll
        for (int mi = 0; mi < 2; ++mi)
          yaccL[mp * 2 + mi][cf] = MFMA(pa[mi], gl, yaccL[mp * 2 + mi][cf]);
      }
    }
    __syncthreads();  // g/P reads done before next stage
  }
  // ---- publish l, epilogue via f32 LDS transpose (2 chunks of 32 rows)
  if ((l & 15) == 0)
#pragma unroll
    for (int r = 0; r < 4; ++r) sL[w * 16 + ((l >> 4) << 2) + r] = lrow[r];
  __syncthreads();
  float* sOutF = (float*)U;
  for (int c = 0; c < 2; ++c) {
#pragma unroll
    for (int mf2 = 0; mf2 < 2; ++mf2) {
      int mf = c * 2 + mf2;
#pragma unroll
      for (int r = 0; r < 4; ++r) {
        int row = mf * 16 + ((l >> 4) << 2) + r;
        float linv = 1.f / sL[row];
        int rl = row - c * 32;
#pragma unroll
        for (int cf = 0; cf < 4; ++cf)
          sOutF[rl * 264 + w * 64 + cf * 16 + (l & 15)] =
              (yacc[mf][cf][r] + yaccL[mf][cf][r] * INV2048) * linv;
      }
    }
    __syncthreads();
    int row = tid >> 3, cc0 = (tid & 7) * 32;
    size_t ob = ((size_t)b * TT + i0 + c * 32 + row) * 256 + cc0;
    f16 hv[32], lv[32];
#pragma unroll
    for (int e = 0; e < 32; ++e) {
      float v = sOutF[row * 264 + cc0 + e];
      f16 h = (f16)v;
      hv[e] = h;
      lv[e] = (f16)((v - (float)h) * SC2048);
    }
#pragma unroll
    for (int q8 = 0; q8 < 4; ++q8) {
      *(f16x8*)&y_h[ob + q8 * 8] = *(f16x8*)(hv + q8 * 8);
      *(f16x8*)&y_l[ob + q8 * 8] = *(f16x8*)(lv + q8 * 8);
    }
    __syncthreads();
  }
}

// ---------------------------------------------------------------------------
__global__ void zero_stats(double* s) { s[threadIdx.x] = 0.0; }

__global__ void bn_stats(const double* __restrict__ osum,
                         const double* __restrict__ osumsq,
                         float* __restrict__ mean, float* __restrict__ rstd) {
  int o = threadIdx.x;
  if (o < CC) {
    const double inv = 1.0 / (double)(BB * TT);
    double mu = osum[o] * inv;
    double var = osumsq[o] * inv - mu * mu;
    mean[o] = (float)mu;
    rstd[o] = (float)(1.0 / sqrt(var + (double)EPSV));
  }
}

__global__ __launch_bounds__(256) void bn_apply(
    float* __restrict__ out, const float* __restrict__ x,
    const float* __restrict__ mean, const float* __restrict__ rstd,
    const float* __restrict__ gamma, const float* __restrict__ beta) {
  const size_t n4 = (size_t)BB * CC * TT / 4;
  for (size_t idx = (size_t)blockIdx.x * blockDim.x + threadIdx.x; idx < n4;
       idx += (size_t)gridDim.x * blockDim.x) {
    size_t e = idx * 4;
    int o = (int)((e / TT) % CC);
    float4 wv = ((const float4*)out)[idx];
    float4 xv = ((const float4*)x)[idx];
    float mu = mean[o], rs = rstd[o], ga = gamma[o], be = beta[o];
    float4 r;
    r.x = fmaxf((wv.x - mu) * rs * ga + be, 0.f) + xv.x;
    r.y = fmaxf((wv.y - mu) * rs * ga + be, 0.f) + xv.y;
    r.z = fmaxf((wv.z - mu) * rs * ga + be, 0.f) + xv.z;
    r.w = fmaxf((wv.w - mu) * rs * ga + be, 0.f) + xv.w;
    ((float4*)out)[idx] = r;
  }
}

// ===========================================================================
// Fallback fp32 path (round-3, known-good) — used if ws too small.
// ===========================================================================
template <int M, int K, bool STATS>
__global__ __launch_bounds__(256) void gemm_proj(
    const float* __restrict__ W, const float* __restrict__ bias,
    const float* __restrict__ X, float* __restrict__ Out,
    double* __restrict__ osum, double* __restrict__ osumsq) {
  __shared__ float Ws[16][65];
  __shared__ float Xs[16][65];
  const int bt = blockIdx.x * 64, bm = blockIdx.y * 64, b = blockIdx.z;
  const int tid = threadIdx.x, tx = tid & 15, ty = tid >> 4;
  const float* Xb = X + (size_t)b * K * TT;
  float acc[4][4] = {};
  for (int kb = 0; kb < K; kb += 16) {
#pragma unroll
    for (int r = 0; r < 4; ++r) {
      int idx = tid + r * 256;
      int m = idx >> 4, k = idx & 15;
      Ws[k][m] = W[(size_t)(bm + m) * K + kb + k];
      int kx = idx >> 6, t = idx & 63;
      Xs[kx][t] = Xb[(size_t)(kb + kx) * TT + bt + t];
    }
    __syncthreads();
#pragma unroll
    for (int k = 0; k < 16; ++k) {
      float a[4], bv[4];
#pragma unroll
      for (int i = 0; i < 4; ++i) a[i] = Ws[k][ty * 4 + i];
#pragma unroll
      for (int j = 0; j < 4; ++j) bv[j] = Xs[k][tx * 4 + j];
#pragma unroll
      for (int i = 0; i < 4; ++i)
#pragma unroll
        for (int j = 0; j < 4; ++j) acc[i][j] += a[i] * bv[j];
    }
    __syncthreads();
  }
#pragma unroll
  for (int i = 0; i < 4; ++i) {
    int m = bm + ty * 4 + i;
    float bv = bias[m];
    double rs = 0.0, rq = 0.0;
#pragma unroll
    for (int j = 0; j < 4; ++j) {
      float v = acc[i][j] + bv;
      Out[((size_t)b * M + m) * TT + bt + tx * 4 + j] = v;
      if (STATS) {
        rs += (double)v;
        rq += (double)v * (double)v;
      }
    }
    if (STATS) {
#pragma unroll
      for (int s = 8; s >= 1; s >>= 1) {
        rs += __shfl_xor(rs, s, 16);
        rq += __shfl_xor(rq, s, 16);
      }
      if (tx == 0) {
        atomicAdd(&osum[m], rs);
        atomicAdd(&osumsq[m], rq);
      }
    }
  }
}

__global__ __launch_bounds__(256) void attn_flash(
    const float* __restrict__ th, const float* __restrict__ ph,
    const float* __restrict__ gx, float* __restrict__ y) {
  __shared__ float As[16][65];
  __shared__ float Bs[16][65];
  __shared__ float Ps[64][65];
  __shared__ float Gs[64][65];
  __shared__ float mScale[64];
  __shared__ float lArr[64];
  const int i0 = blockIdx.x * 64, b = blockIdx.y;
  const int tid = threadIdx.x, tx = tid & 15, ty = tid >> 4;
  const float* thb = th + (size_t)b * ICC * TT;
  const float* phb = ph + (size_t)b * ICC * TT;
  const float* gb = gx + (size_t)b * ICC * TT;
  float m[4], l[4];
#pragma unroll
  for (int i = 0; i < 4; ++i) {
    m[i] = -1e30f;
    l[i] = 0.f;
  }
  float acc[4][4][4] = {};
  for (int j0 = 0; j0 < TT; j0 += 64) {
    float S[4][4] = {};
    for (int cb = 0; cb < ICC; cb += 16) {
#pragma unroll
      for (int r = 0; r < 4; ++r) {
        int idx = tid + r * 256;
        int k = idx >> 6, col = idx & 63;
        As[k][col] = thb[(size_t)(cb + k) * TT + i0 + col];
        Bs[k][col] = phb[(size_t)(cb + k) * TT + j0 + col];
      }
      __syncthreads();
#pragma unroll
      for (int k = 0; k < 16; ++k) {
        float a[4], bv[4];
#pragma unroll
        for (int i = 0; i < 4; ++i) a[i] = As[k][ty * 4 + i];
#pragma unroll
        for (int j = 0; j < 4; ++j) bv[j] = Bs[k][tx * 4 + j];
#pragma unroll
        for (int i = 0; i < 4; ++i)
#pragma unroll
          for (int j = 0; j < 4; ++j) S[i][j] += a[i] * bv[j];
      }
      __syncthreads();
    }
    float sc[4];
#pragma unroll
    for (int i = 0; i < 4; ++i) {
      float mc = S[i][0];
#pragma unroll
      for (int j = 1; j < 4; ++j) mc = fmaxf(mc, S[i][j]);
#pragma unroll
      for (int s = 8; s >= 1; s >>= 1) mc = fmaxf(mc, __shfl_xor(mc, s, 16));
      float mn = fmaxf(m[i], mc);
      sc[i] = __expf(m[i] - mn);
      float lsum = 0.f;
#pragma unroll
      for (int j = 0; j < 4; ++j) {
        float p = __expf(S[i][j] - mn);
        S[i][j] = p;
        lsum += p;
      }
#pragma unroll
      for (int s = 8; s >= 1; s >>= 1) lsum += __shfl_xor(lsum, s, 16);
      l[i] = l[i] * sc[i] + lsum;
      m[i] = mn;
#pragma unroll
      for (int j = 0; j < 4; ++j) Ps[ty * 4 + i][tx * 4 + j] = S[i][j];
    }
    if (tx == 0) {
#pragma unroll
      for (int i = 0; i < 4; ++i) mScale[ty * 4 + i] = sc[i];
    }
    __syncthreads();
#pragma unroll
    for (int cq = 0; cq < 4; ++cq) {
#pragma unroll
      for (int r = 0; r < 16; ++r) {
        int idx = tid + r * 256;
        int cpr = idx >> 6, j = idx & 63;
        Gs[cpr][j] = gb[(size_t)(cq * 64 + cpr) * TT + j0 + j];
      }
      __syncthreads();
      float scj[4];
#pragma unroll
      for (int jq = 0; jq < 4; ++jq) scj[jq] = mScale[tx * 4 + jq];
#pragma unroll
      for (int ci = 0; ci < 4; ++ci)
#pragma unroll
        for (int jq = 0; jq < 4; ++jq) acc[cq][ci][jq] *= scj[jq];
      for (int j = 0; j < 64; ++j) {
        float a[4], p[4];
#pragma unroll
        for (int ci = 0; ci < 4; ++ci) a[ci] = Gs[ty * 4 + ci][j];
#pragma unroll
        for (int jq = 0; jq < 4; ++jq) p[jq] = Ps[tx * 4 + jq][j];
#pragma unroll
        for (int ci = 0; ci < 4; ++ci)
#pragma unroll
          for (int jq = 0; jq < 4; ++jq) acc[cq][ci][jq] += a[ci] * p[jq];
      }
      __syncthreads();
    }
  }
  if (tx == 0) {
#pragma unroll
    for (int i = 0; i < 4; ++i) lArr[ty * 4 + i] = l[i];
  }
  __syncthreads();
  float linv[4];
#pragma unroll
  for (int jq = 0; jq < 4; ++jq) linv[jq] = 1.f / lArr[tx * 4 + jq];
#pragma unroll
  for (int cq = 0; cq < 4; ++cq)
#pragma unroll
    for (int ci = 0; ci < 4; ++ci)
#pragma unroll
      for (int jq = 0; jq < 4; ++jq)
        y[((size_t)b * ICC + cq * 64 + ty * 4 + ci) * TT + i0 + tx * 4 + jq] =
            acc[cq][ci][jq] * linv[jq];
}

// ---------------------------------------------------------------------------
extern "C" void kernel_launch(void* const* d_in, const int* in_sizes, int n_in,
                              void* d_out, int out_size, void* d_ws,
                              size_t ws_size, hipStream_t stream) {
  const float* x = (const float*)d_in[0];
  const float* g_w = (const float*)d_in[1];
  const float* g_b = (const float*)d_in[2];
  const float* th_w = (const float*)d_in[3];
  const float* th_b = (const float*)d_in[4];
  const float* ph_w = (const float*)d_in[5];
  const float* ph_b = (const float*)d_in[6];
  const float* W_w = (const float*)d_in[7];
  const float* W_b = (const float*)d_in[8];
  const float* gamma = (const float*)d_in[9];
  const float* beta = (const float*)d_in[10];
  float* out = (float*)d_out;
  dim3 blk(256);

  const size_t NP = (size_t)BB * TT * ICC;  // 4,194,304
  const size_t NW = 131072;                 // 256*512
  const size_t need = (8 * NP + 8 * NW) * sizeof(f16) + 8192 + 4096;

  if (ws_size >= need) {
    // ---------------- fast MFMA path ----------------
    f16* p = (f16*)d_ws;
    f16 *thH = p, *thL = thH + NP, *phH = thL + NP, *phL = phH + NP;
    f16 *gH = phL + NP, *gL = gH + NP, *yH = gL + NP, *yL = yH + NP;
    f16* wp = yL + NP;
    f16 *gwH = wp, *gwL = gwH + NW, *twH = gwL + NW, *twL = twH + NW;
    f16 *pwH = twL + NW, *pwL = pwH + NW, *wwH = pwL + NW, *wwL = wwH + NW;
    double* statd = (double*)(wwL + NW);
    float* meanb = (float*)(statd + 1024);
    float* rstdb = meanb + 512;
    f16* xTh = (f16*)d_out;  // xT hi/lo lives in d_out (dead before W-conv)
    f16* xTl = xTh + (size_t)BB * TT * CC;

    split_transpose_x<<<dim3(TT / 32, CC / 32, BB), dim3(32, 8), 0, stream>>>(
        x, xTh, xTl);
    split_w<<<512, 256, 0, stream>>>(g_w, gwH, gwL, (int)NW);
    split_w<<<512, 256, 0, stream>>>(th_w, twH, twL, (int)NW);
    split_w<<<512, 256, 0, stream>>>(ph_w, pwH, pwL, (int)NW);
    split_w<<<512, 256, 0, stream>>>(W_w, wwH, wwL, (int)NW);
    zero_stats<<<1, 1024, 0, stream>>>(statd);

    // theta/phi: D[t][ic] = xT * W^T   (M=T, N=IC, K=C, bias on N)
    gemm_nt<TT, ICC, CC, true, false><<<dim3(2, 16, BB), blk, 0, stream>>>(
        xTh, xTl, (long)TT * CC, twH, twL, 0, th_b, thH, thL, nullptr,
        (long)TT * ICC, nullptr, nullptr);
    gemm_nt<TT, ICC, CC, true, false><<<dim3(2, 16, BB), blk, 0, stream>>>(
        xTh, xTl, (long)TT * CC, pwH, pwL, 0, ph_b, phH, phL, nullptr,
        (long)TT * ICC, nullptr, nullptr);
    // g: D[ic][t] = Wg * xT^T   (M=IC, N=T, K=C, bias on M)
    gemm_nt<ICC, TT, CC, false, false><<<dim3(16, 2, BB), blk, 0, stream>>>(
        gwH, gwL, 0, xTh, xTl, (long)TT * CC, g_b, gH, gL, nullptr,
        (long)ICC * TT, nullptr, nullptr);
    // attention -> y [b][t][ic]
    attn_mfma<<<256, blk, 0, stream>>>(thH, thL, phH, phL, gH, gL, yH, yL);
    // W conv: D[o][t] -> d_out + BN stats  (M=C, N=T, K=IC, bias on M)
    gemm_nt<CC, TT, ICC, false, true><<<dim3(16, 4, BB), blk, 0, stream>>>(
        wwH, wwL, 0, yH, yL, (long)TT * ICC, W_b, nullptr, nullptr, out,
        (long)CC * TT, statd, statd + CC);
    bn_stats<<<1, 512, 0, stream>>>(statd, statd + CC, meanb, rstdb);
    bn_apply<<<2048, 256, 0, stream>>>(out, x, meanb, rstdb, gamma, beta);
  } else {
    // ---------------- fallback fp32 path ----------------
    float* ws = (float*)d_ws;
    const size_t np = (size_t)BB * ICC * TT;
    float* thb = ws;
    float* phb = ws + np;
    float* gbuf = ws + 2 * np;
    float* yb = thb;
    double* statd = (double*)(ws + 3 * np);
    float* meanb = (float*)(statd + 1024);
    float* rstdb = meanb + 512;
    gemm_proj<ICC, CC, false><<<dim3(TT / 64, ICC / 64, BB), blk, 0, stream>>>(
        th_w, th_b, x, thb, nullptr, nullptr);
    gemm_proj<ICC, CC, false><<<dim3(TT / 64, ICC / 64, BB), blk, 0, stream>>>(
        ph_w, ph_b, x, phb, nullptr, nullptr);
    gemm_proj<ICC, CC, false><<<dim3(TT / 64, ICC / 64, BB), blk, 0, stream>>>(
        g_w, g_b, x, gbuf, nullptr, nullptr);
    attn_flash<<<dim3(TT / 64, BB), blk, 0, stream>>>(thb, phb, gbuf, yb);
    zero_stats<<<1, 1024, 0, stream>>>(statd);
    gemm_proj<CC, ICC, true><<<dim3(TT / 64, CC / 64, BB), blk, 0, stream>>>(
        W_w, W_b, yb, out, statd, statd + CC);
    bn_stats<<<1, 512, 0, stream>>>(statd, statd + CC, meanb, rstdb);
    bn_apply<<<2048, 256, 0, stream>>>(out, x, meanb, rstdb, gamma, beta);
  }
}

// Round 7
// 493.036 us; speedup vs baseline: 4.1745x; 1.0882x over previous
//
#include <hip/hip_runtime.h>
#include <math.h>

#define BB 8
#define CC 512
#define TT 2048
#define ICC 256
#define EPSV 1e-5f
#define SC2048 2048.0f
#define INV2048 4.8828125e-4f

typedef _Float16 f16;
typedef __attribute__((ext_vector_type(8))) _Float16 f16x8;
typedef __attribute__((ext_vector_type(4))) float f32x4;

#define MFMA(a, b, c) __builtin_amdgcn_mfma_f32_16x16x32_f16(a, b, c, 0, 0, 0)

__device__ __forceinline__ int swz(int byte, int row) {
  return byte ^ ((row & 7) << 4);
}

// ---------------------------------------------------------------------------
// P0: x[b][c][t] f32 -> xT hi / scaled-lo f16 [b][t][c]
// ---------------------------------------------------------------------------
__global__ __launch_bounds__(256) void split_transpose_x(
    const float* __restrict__ x, f16* __restrict__ xh, f16* __restrict__ xl) {
  __shared__ float tile[32][33];
  const int tx = threadIdx.x, ty = threadIdx.y;
  const int t0 = blockIdx.x * 32, c0 = blockIdx.y * 32, b = blockIdx.z;
#pragma unroll
  for (int k = 0; k < 4; ++k)
    tile[ty + 8 * k][tx] = x[((size_t)b * CC + c0 + ty + 8 * k) * TT + t0 + tx];
  __syncthreads();
#pragma unroll
  for (int k = 0; k < 4; ++k) {
    float v = tile[tx][ty + 8 * k];
    size_t o = ((size_t)b * TT + t0 + ty + 8 * k) * CC + c0 + tx;
    f16 h = (f16)v;
    xh[o] = h;
    xl[o] = (f16)((v - (float)h) * SC2048);
  }
}

__global__ void split_w(const float* __restrict__ src, f16* __restrict__ h,
                        f16* __restrict__ lo, int n) {
  int i = blockIdx.x * 256 + threadIdx.x;
  if (i < n) {
    float v = src[i];
    f16 a = (f16)v;
    h[i] = a;
    lo[i] = (f16)((v - (float)a) * SC2048);
  }
}

// ---------------------------------------------------------------------------
// NT GEMM: D[M][N] = A[M][K] * B[N][K]^T + bias.  fp16 split with SCALED lo
// (lo' = (v-hi)*2048) and separate correction accumulator:
//   D = acc(hi*hi) + accL(lo'*hi + hi*lo') / 2048
// Block 128x128x(K-step 32), 4 waves each 64x64. grid (N/128, M/128, batch).
// ---------------------------------------------------------------------------
template <int M, int N, int K, bool BIAS_N, bool F32OUT>
__global__ __launch_bounds__(256) void gemm_nt(
    const f16* __restrict__ Ah, const f16* __restrict__ Al, long strideA,
    const f16* __restrict__ Bh, const f16* __restrict__ Bl, long strideB,
    const float* __restrict__ bias, f16* __restrict__ Oh, f16* __restrict__ Ol,
    float* __restrict__ Of, long strideO, double* __restrict__ osum,
    double* __restrict__ osumsq) {
  __shared__ f16 sAh[4096], sAl[4096], sBh[4096], sBl[4096];
  __shared__ float sOut[F32OUT ? 1 : 32 * 132];
  const int tid = threadIdx.x;
  const int w = tid >> 6, l = tid & 63;
  const int bn = blockIdx.x * 128, bm = blockIdx.y * 128;
  const size_t baseA = (size_t)blockIdx.z * strideA;
  const size_t baseB = (size_t)blockIdx.z * strideB;
  const size_t baseO = (size_t)blockIdx.z * strideO;
  const int m0 = (w >> 1) * 64, n0 = (w & 1) * 64;
  char* cAh = (char*)sAh;
  char* cAl = (char*)sAl;
  char* cBh = (char*)sBh;
  char* cBl = (char*)sBl;

  f32x4 acc[4][4], accL[4][4];
#pragma unroll
  for (int i = 0; i < 4; ++i)
#pragma unroll
    for (int j = 0; j < 4; ++j) {
      acc[i][j] = (f32x4){0.f, 0.f, 0.f, 0.f};
      accL[i][j] = (f32x4){0.f, 0.f, 0.f, 0.f};
    }

  for (int kb = 0; kb < K; kb += 32) {
    __syncthreads();
#pragma unroll
    for (int rep = 0; rep < 2; ++rep) {
      int slot = tid + rep * 256;  // 0..511
      int row = slot >> 2, ks = slot & 3;
      int byte = swz(row * 64 + ks * 16, row);
      size_t ga = baseA + (size_t)(bm + row) * K + kb + ks * 8;
      size_t gb = baseB + (size_t)(bn + row) * K + kb + ks * 8;
      *(f16x8*)(cAh + byte) = *(const f16x8*)(Ah + ga);
      *(f16x8*)(cAl + byte) = *(const f16x8*)(Al + ga);
      *(f16x8*)(cBh + byte) = *(const f16x8*)(Bh + gb);
      *(f16x8*)(cBl + byte) = *(const f16x8*)(Bl + gb);
    }
    __syncthreads();
    f16x8 ah[4], al[4];
#pragma unroll
    for (int mf = 0; mf < 4; ++mf) {
      int row = m0 + mf * 16 + (l & 15);
      int byte = swz(row * 64 + ((l >> 4) << 4), row);
      ah[mf] = *(const f16x8*)(cAh + byte);
      al[mf] = *(const f16x8*)(cAl + byte);
    }
#pragma unroll
    for (int nf = 0; nf < 4; ++nf) {
      int row = n0 + nf * 16 + (l & 15);
      int byte = swz(row * 64 + ((l >> 4) << 4), row);
      f16x8 bh = *(const f16x8*)(cBh + byte);
      f16x8 bl = *(const f16x8*)(cBl + byte);
#pragma unroll
      for (int mf = 0; mf < 4; ++mf)
        acc[mf][nf] = MFMA(ah[mf], bh, acc[mf][nf]);
#pragma unroll
      for (int mf = 0; mf < 4; ++mf)
        accL[mf][nf] = MFMA(al[mf], bh, accL[mf][nf]);
#pragma unroll
      for (int mf = 0; mf < 4; ++mf)
        accL[mf][nf] = MFMA(ah[mf], bl, accL[mf][nf]);
    }
  }

  if (F32OUT) {
#pragma unroll
    for (int mf = 0; mf < 4; ++mf)
#pragma unroll
      for (int r = 0; r < 4; ++r) {
        int mrow = bm + m0 + mf * 16 + ((l >> 4) << 2) + r;
        float bv = bias[mrow];
        double s = 0.0, q = 0.0;
#pragma unroll
        for (int nf = 0; nf < 4; ++nf) {
          float v = acc[mf][nf][r] + accL[mf][nf][r] * INV2048 + bv;
          Of[baseO + (size_t)mrow * N + bn + n0 + nf * 16 + (l & 15)] = v;
          s += (double)v;
          q += (double)v * (double)v;
        }
#pragma unroll
        for (int sh = 8; sh >= 1; sh >>= 1) {
          s += __shfl_xor(s, sh);
          q += __shfl_xor(q, sh);
        }
        if ((l & 15) == 0) {
          atomicAdd(&osum[mrow], s);
          atomicAdd(&osumsq[mrow], q);
        }
      }
  } else {
    // LDS transpose epilogue, 32-row chunks (rl includes wave m0 offset).
    for (int c = 0; c < 4; ++c) {
      __syncthreads();
      if ((w >> 1) == (c >> 1)) {
#pragma unroll
        for (int mf2 = 0; mf2 < 2; ++mf2) {
          int mf = (c & 1) * 2 + mf2;
          int rl = m0 - c * 32 + mf * 16 + ((l >> 4) << 2);
#pragma unroll
          for (int nf = 0; nf < 4; ++nf)
#pragma unroll
            for (int r = 0; r < 4; ++r)
              sOut[(rl + r) * 132 + n0 + nf * 16 + (l & 15)] =
                  acc[mf][nf][r] + accL[mf][nf][r] * INV2048;
        }
      }
      __syncthreads();
      int row = tid >> 3, cc0 = (tid & 7) * 16;
      size_t gm = bm + c * 32 + row;
      size_t ob = baseO + gm * (size_t)N + bn + cc0;
      f16 hv[16], lv[16];
#pragma unroll
      for (int e = 0; e < 16; ++e) {
        float v = sOut[row * 132 + cc0 + e];
        v += BIAS_N ? bias[bn + cc0 + e] : bias[gm];
        f16 h = (f16)v;
        hv[e] = h;
        lv[e] = (f16)((v - (float)h) * SC2048);
      }
      *(f16x8*)&Oh[ob] = *(f16x8*)hv;
      *(f16x8*)&Oh[ob + 8] = *(f16x8*)(hv + 8);
      *(f16x8*)&Ol[ob] = *(f16x8*)lv;
      *(f16x8*)&Ol[ob + 8] = *(f16x8*)(lv + 8);
    }
  }
}

// ---------------------------------------------------------------------------
// Fused flash attention, fp16-split MFMA, double-buffered pipeline (r7):
//  - phi and g in SEPARATE double-buffered LDS regions (no time-sharing)
//  - chunk jc+1 global loads issued at top of iter jc (regs), LDS-written
//    after PV -> HBM/L2 latency hidden under QK+softmax+PV
//  - 2 barriers per chunk (was 4)
// ---------------------------------------------------------------------------
__global__ __launch_bounds__(256, 1) void attn_mfma(
    const f16* __restrict__ th_h, const f16* __restrict__ th_l,
    const f16* __restrict__ ph_h, const f16* __restrict__ ph_l,
    const f16* __restrict__ g_h, const f16* __restrict__ g_l,
    f16* __restrict__ y_h, f16* __restrict__ y_l) {
  __shared__ f16 sPhiH[2][8192];  // phi hi  [buf][32 j][256 c] swizzled, 32KB
  __shared__ f16 sPhiL[2][8192];  // phi lo'
  __shared__ f16 sGH[2][8192];    // g hi    [buf][256 c'][32 j] swizzled
  __shared__ f16 sGL[2][8192];    // g lo'
  __shared__ f16 sP[2048], sPl[2048];  // P hi / scaled-lo [64][32] swizzled
  __shared__ float sSc[64], sL[64];
  const int tid = threadIdx.x, w = tid >> 6, l = tid & 63;
  const int b = blockIdx.x & 7;
  const int i0 = (blockIdx.x >> 3) * 64;

  // theta fragments in registers
  const size_t tbase =
      ((size_t)b * TT + i0 + w * 16 + (l & 15)) * 256 + ((l >> 4) << 3);
  f16x8 qh[8], ql[8];
#pragma unroll
  for (int kf = 0; kf < 8; ++kf) {
    qh[kf] = *(const f16x8*)(th_h + tbase + kf * 32);
    ql[kf] = *(const f16x8*)(th_l + tbase + kf * 32);
  }
  f32x4 yacc[4][4], yaccL[4][4];
#pragma unroll
  for (int i = 0; i < 4; ++i)
#pragma unroll
    for (int j = 0; j < 4; ++j) {
      yacc[i][j] = (f32x4){0.f, 0.f, 0.f, 0.f};
      yaccL[i][j] = (f32x4){0.f, 0.f, 0.f, 0.f};
    }
  float mrow[4], lrow[4];
#pragma unroll
  for (int r = 0; r < 4; ++r) {
    mrow[r] = -3e38f;
    lrow[r] = 0.f;
  }

  // ---- prologue: stage chunk 0 into buffers 0
  {
    f16x8 prh[4], prl[4], grh[4], grl[4];
#pragma unroll
    for (int rep = 0; rep < 4; ++rep) {
      int slot = tid + rep * 256;
      int prow = slot >> 5, pks = slot & 31;
      size_t pa = ((size_t)b * TT + prow) * 256 + pks * 8;
      prh[rep] = *(const f16x8*)(ph_h + pa);
      prl[rep] = *(const f16x8*)(ph_l + pa);
      int grow = slot >> 2, gks = slot & 3;
      size_t ga = ((size_t)b * 256 + grow) * TT + gks * 8;
      grh[rep] = *(const f16x8*)(g_h + ga);
      grl[rep] = *(const f16x8*)(g_l + ga);
    }
#pragma unroll
    for (int rep = 0; rep < 4; ++rep) {
      int slot = tid + rep * 256;
      int prow = slot >> 5, pks = slot & 31;
      int pb = swz(prow * 512 + pks * 16, prow);
      *(f16x8*)((char*)&sPhiH[0][0] + pb) = prh[rep];
      *(f16x8*)((char*)&sPhiL[0][0] + pb) = prl[rep];
      int grow = slot >> 2, gks = slot & 3;
      int gb2 = swz(grow * 64 + gks * 16, grow);
      *(f16x8*)((char*)&sGH[0][0] + gb2) = grh[rep];
      *(f16x8*)((char*)&sGL[0][0] + gb2) = grl[rep];
    }
    __syncthreads();
  }

  for (int jc = 0; jc < 64; ++jc) {
    const int cur = jc & 1, nxt = cur ^ 1;
    const int j0n = (jc + 1) * 32;
    // ---- issue next-chunk global loads (held in regs until after PV)
    f16x8 prh[4], prl[4], grh[4], grl[4];
    if (jc < 63) {
#pragma unroll
      for (int rep = 0; rep < 4; ++rep) {
        int slot = tid + rep * 256;
        int prow = slot >> 5, pks = slot & 31;
        size_t pa = ((size_t)b * TT + j0n + prow) * 256 + pks * 8;
        prh[rep] = *(const f16x8*)(ph_h + pa);
        prl[rep] = *(const f16x8*)(ph_l + pa);
        int grow = slot >> 2, gks = slot & 3;
        size_t ga = ((size_t)b * 256 + grow) * TT + j0n + gks * 8;
        grh[rep] = *(const f16x8*)(g_h + ga);
        grl[rep] = *(const f16x8*)(g_l + ga);
      }
    }
    // ---- QK^T from phi[cur] (hi + 2 correction passes)
    f32x4 s4[2] = {(f32x4){0.f, 0.f, 0.f, 0.f}, (f32x4){0.f, 0.f, 0.f, 0.f}};
    f32x4 s4L[2] = {(f32x4){0.f, 0.f, 0.f, 0.f}, (f32x4){0.f, 0.f, 0.f, 0.f}};
#pragma unroll
    for (int kf = 0; kf < 8; ++kf) {
#pragma unroll
      for (int jf = 0; jf < 2; ++jf) {
        int row = jf * 16 + (l & 15);
        int byte = swz(row * 512 + kf * 64 + ((l >> 4) << 4), row);
        f16x8 bh = *(const f16x8*)((char*)&sPhiH[cur][0] + byte);
        f16x8 bl = *(const f16x8*)((char*)&sPhiL[cur][0] + byte);
        s4[jf] = MFMA(qh[kf], bh, s4[jf]);
        s4L[jf] = MFMA(ql[kf], bh, s4L[jf]);
        s4L[jf] = MFMA(qh[kf], bl, s4L[jf]);
      }
    }
    // ---- online softmax
#pragma unroll
    for (int r = 0; r < 4; ++r) {
      float sv0 = s4[0][r] + s4L[0][r] * INV2048;
      float sv1 = s4[1][r] + s4L[1][r] * INV2048;
      float mx = fmaxf(sv0, sv1);
#pragma unroll
      for (int sh = 8; sh >= 1; sh >>= 1) mx = fmaxf(mx, __shfl_xor(mx, sh));
      float mn = fmaxf(mrow[r], mx);
      float sc = __expf(mrow[r] - mn);
      mrow[r] = mn;
      float p0 = __expf(sv0 - mn);
      float p1 = __expf(sv1 - mn);
      float ls = p0 + p1;
#pragma unroll
      for (int sh = 8; sh >= 1; sh >>= 1) ls += __shfl_xor(ls, sh);
      lrow[r] = lrow[r] * sc + ls;
      int il = w * 16 + ((l >> 4) << 2) + r;
      int jj0 = (l & 15), jj1 = 16 + (l & 15);
      f16 h0 = (f16)p0, h1 = (f16)p1;
      *(f16*)((char*)sP + swz(il * 64 + jj0 * 2, il)) = h0;
      *(f16*)((char*)sP + swz(il * 64 + jj1 * 2, il)) = h1;
      *(f16*)((char*)sPl + swz(il * 64 + jj0 * 2, il)) =
          (f16)((p0 - (float)h0) * SC2048);
      *(f16*)((char*)sPl + swz(il * 64 + jj1 * 2, il)) =
          (f16)((p1 - (float)h1) * SC2048);
      if ((l & 15) == 0) sSc[il] = sc;
    }
    __syncthreads();  // barrier 1: P/sSc published (prefetch drains here too)
    // ---- rescale accumulators
#pragma unroll
    for (int mf = 0; mf < 4; ++mf)
#pragma unroll
      for (int r = 0; r < 4; ++r) {
        float s0 = sSc[mf * 16 + ((l >> 4) << 2) + r];
#pragma unroll
        for (int cf = 0; cf < 4; ++cf) {
          yacc[mf][cf][r] *= s0;
          yaccL[mf][cf][r] *= s0;
        }
      }
    // ---- PV from sP + g[cur] (3-pass split)
#pragma unroll
    for (int mp = 0; mp < 2; ++mp) {
      f16x8 pa[2], paL[2];
#pragma unroll
      for (int mi = 0; mi < 2; ++mi) {
        int row = (mp * 2 + mi) * 16 + (l & 15);
        int byte = swz(row * 64 + ((l >> 4) << 4), row);
        pa[mi] = *(const f16x8*)((char*)sP + byte);
        paL[mi] = *(const f16x8*)((char*)sPl + byte);
      }
#pragma unroll
      for (int cf = 0; cf < 4; ++cf) {
        int crow = w * 64 + cf * 16 + (l & 15);
        int byte = swz(crow * 64 + ((l >> 4) << 4), crow);
        f16x8 gh = *(const f16x8*)((char*)&sGH[cur][0] + byte);
        f16x8 gl = *(const f16x8*)((char*)&sGL[cur][0] + byte);
#pragma unroll
        for (int mi = 0; mi < 2; ++mi)
          yacc[mp * 2 + mi][cf] = MFMA(pa[mi], gh, yacc[mp * 2 + mi][cf]);
#pragma unroll
        for (int mi = 0; mi < 2; ++mi)
          yaccL[mp * 2 + mi][cf] = MFMA(paL[mi], gh, yaccL[mp * 2 + mi][cf]);
#pragma unroll
        for (int mi = 0; mi < 2; ++mi)
          yaccL[mp * 2 + mi][cf] = MFMA(pa[mi], gl, yaccL[mp * 2 + mi][cf]);
      }
    }
    // ---- write next-chunk staging regs into [nxt] buffers
    if (jc < 63) {
#pragma unroll
      for (int rep = 0; rep < 4; ++rep) {
        int slot = tid + rep * 256;
        int prow = slot >> 5, pks = slot & 31;
        int pb = swz(prow * 512 + pks * 16, prow);
        *(f16x8*)((char*)&sPhiH[nxt][0] + pb) = prh[rep];
        *(f16x8*)((char*)&sPhiL[nxt][0] + pb) = prl[rep];
        int grow = slot >> 2, gks = slot & 3;
        int gb2 = swz(grow * 64 + gks * 16, grow);
        *(f16x8*)((char*)&sGH[nxt][0] + gb2) = grh[rep];
        *(f16x8*)((char*)&sGL[nxt][0] + gb2) = grl[rep];
      }
    }
    __syncthreads();  // barrier 2: sP reads done; [nxt] staging visible
  }
  // ---- publish l, epilogue via f32 LDS transpose (4 chunks of 16 rows)
  if ((l & 15) == 0)
#pragma unroll
    for (int r = 0; r < 4; ++r) sL[w * 16 + ((l >> 4) << 2) + r] = lrow[r];
  __syncthreads();
  float* sOutF = (float*)&sPhiH[0][0];  // 32KB scratch (phi region, dead now)
  for (int c2 = 0; c2 < 4; ++c2) {
#pragma unroll
    for (int r = 0; r < 4; ++r) {
      int row = c2 * 16 + ((l >> 4) << 2) + r;
      float linv = 1.f / sL[row];
      int rl = row & 15;
#pragma unroll
      for (int cf = 0; cf < 4; ++cf)
        sOutF[rl * 264 + w * 64 + cf * 16 + (l & 15)] =
            (yacc[c2][cf][r] + yaccL[c2][cf][r] * INV2048) * linv;
    }
    __syncthreads();
    int row = tid >> 4, cc0 = (tid & 15) * 16;
    size_t ob = ((size_t)b * TT + i0 + c2 * 16 + row) * 256 + cc0;
    f16 hv[16], lv[16];
#pragma unroll
    for (int e = 0; e < 16; ++e) {
      float v = sOutF[row * 264 + cc0 + e];
      f16 h = (f16)v;
      hv[e] = h;
      lv[e] = (f16)((v - (float)h) * SC2048);
    }
    *(f16x8*)&y_h[ob] = *(f16x8*)hv;
    *(f16x8*)&y_h[ob + 8] = *(f16x8*)(hv + 8);
    *(f16x8*)&y_l[ob] = *(f16x8*)lv;
    *(f16x8*)&y_l[ob + 8] = *(f16x8*)(lv + 8);
    __syncthreads();
  }
}

// ---------------------------------------------------------------------------
__global__ void zero_stats(double* s) { s[threadIdx.x] = 0.0; }

__global__ void bn_stats(const double* __restrict__ osum,
                         const double* __restrict__ osumsq,
                         float* __restrict__ mean, float* __restrict__ rstd) {
  int o = threadIdx.x;
  if (o < CC) {
    const double inv = 1.0 / (double)(BB * TT);
    double mu = osum[o] * inv;
    double var = osumsq[o] * inv - mu * mu;
    mean[o] = (float)mu;
    rstd[o] = (float)(1.0 / sqrt(var + (double)EPSV));
  }
}

__global__ __launch_bounds__(256) void bn_apply(
    float* __restrict__ out, const float* __restrict__ x,
    const float* __restrict__ mean, const float* __restrict__ rstd,
    const float* __restrict__ gamma, const float* __restrict__ beta) {
  const size_t n4 = (size_t)BB * CC * TT / 4;
  for (size_t idx = (size_t)blockIdx.x * blockDim.x + threadIdx.x; idx < n4;
       idx += (size_t)gridDim.x * blockDim.x) {
    size_t e = idx * 4;
    int o = (int)((e / TT) % CC);
    float4 wv = ((const float4*)out)[idx];
    float4 xv = ((const float4*)x)[idx];
    float mu = mean[o], rs = rstd[o], ga = gamma[o], be = beta[o];
    float4 r;
    r.x = fmaxf((wv.x - mu) * rs * ga + be, 0.f) + xv.x;
    r.y = fmaxf((wv.y - mu) * rs * ga + be, 0.f) + xv.y;
    r.z = fmaxf((wv.z - mu) * rs * ga + be, 0.f) + xv.z;
    r.w = fmaxf((wv.w - mu) * rs * ga + be, 0.f) + xv.w;
    ((float4*)out)[idx] = r;
  }
}

// ===========================================================================
// Fallback fp32 path (round-3, known-good) — used if ws too small.
// ===========================================================================
template <int M, int K, bool STATS>
__global__ __launch_bounds__(256) void gemm_proj(
    const float* __restrict__ W, const float* __restrict__ bias,
    const float* __restrict__ X, float* __restrict__ Out,
    double* __restrict__ osum, double* __restrict__ osumsq) {
  __shared__ float Ws[16][65];
  __shared__ float Xs[16][65];
  const int bt = blockIdx.x * 64, bm = blockIdx.y * 64, b = blockIdx.z;
  const int tid = threadIdx.x, tx = tid & 15, ty = tid >> 4;
  const float* Xb = X + (size_t)b * K * TT;
  float acc[4][4] = {};
  for (int kb = 0; kb < K; kb += 16) {
#pragma unroll
    for (int r = 0; r < 4; ++r) {
      int idx = tid + r * 256;
      int m = idx >> 4, k = idx & 15;
      Ws[k][m] = W[(size_t)(bm + m) * K + kb + k];
      int kx = idx >> 6, t = idx & 63;
      Xs[kx][t] = Xb[(size_t)(kb + kx) * TT + bt + t];
    }
    __syncthreads();
#pragma unroll
    for (int k = 0; k < 16; ++k) {
      float a[4], bv[4];
#pragma unroll
      for (int i = 0; i < 4; ++i) a[i] = Ws[k][ty * 4 + i];
#pragma unroll
      for (int j = 0; j < 4; ++j) bv[j] = Xs[k][tx * 4 + j];
#pragma unroll
      for (int i = 0; i < 4; ++i)
#pragma unroll
        for (int j = 0; j < 4; ++j) acc[i][j] += a[i] * bv[j];
    }
    __syncthreads();
  }
#pragma unroll
  for (int i = 0; i < 4; ++i) {
    int m = bm + ty * 4 + i;
    float bv = bias[m];
    double rs = 0.0, rq = 0.0;
#pragma unroll
    for (int j = 0; j < 4; ++j) {
      float v = acc[i][j] + bv;
      Out[((size_t)b * M + m) * TT + bt + tx * 4 + j] = v;
      if (STATS) {
        rs += (double)v;
        rq += (double)v * (double)v;
      }
    }
    if (STATS) {
#pragma unroll
      for (int s = 8; s >= 1; s >>= 1) {
        rs += __shfl_xor(rs, s, 16);
        rq += __shfl_xor(rq, s, 16);
      }
      if (tx == 0) {
        atomicAdd(&osum[m], rs);
        atomicAdd(&osumsq[m], rq);
      }
    }
  }
}

__global__ __launch_bounds__(256) void attn_flash(
    const float* __restrict__ th, const float* __restrict__ ph,
    const float* __restrict__ gx, float* __restrict__ y) {
  __shared__ float As[16][65];
  __shared__ float Bs[16][65];
  __shared__ float Ps[64][65];
  __shared__ float Gs[64][65];
  __shared__ float mScale[64];
  __shared__ float lArr[64];
  const int i0 = blockIdx.x * 64, b = blockIdx.y;
  const int tid = threadIdx.x, tx = tid & 15, ty = tid >> 4;
  const float* thb = th + (size_t)b * ICC * TT;
  const float* phb = ph + (size_t)b * ICC * TT;
  const float* gb = gx + (size_t)b * ICC * TT;
  float m[4], l[4];
#pragma unroll
  for (int i = 0; i < 4; ++i) {
    m[i] = -1e30f;
    l[i] = 0.f;
  }
  float acc[4][4][4] = {};
  for (int j0 = 0; j0 < TT; j0 += 64) {
    float S[4][4] = {};
    for (int cb = 0; cb < ICC; cb += 16) {
#pragma unroll
      for (int r = 0; r < 4; ++r) {
        int idx = tid + r * 256;
        int k = idx >> 6, col = idx & 63;
        As[k][col] = thb[(size_t)(cb + k) * TT + i0 + col];
        Bs[k][col] = phb[(size_t)(cb + k) * TT + j0 + col];
      }
      __syncthreads();
#pragma unroll
      for (int k = 0; k < 16; ++k) {
        float a[4], bv[4];
#pragma unroll
        for (int i = 0; i < 4; ++i) a[i] = As[k][ty * 4 + i];
#pragma unroll
        for (int j = 0; j < 4; ++j) bv[j] = Bs[k][tx * 4 + j];
#pragma unroll
        for (int i = 0; i < 4; ++i)
#pragma unroll
          for (int j = 0; j < 4; ++j) S[i][j] += a[i] * bv[j];
      }
      __syncthreads();
    }
    float sc[4];
#pragma unroll
    for (int i = 0; i < 4; ++i) {
      float mc = S[i][0];
#pragma unroll
      for (int j = 1; j < 4; ++j) mc = fmaxf(mc, S[i][j]);
#pragma unroll
      for (int s = 8; s >= 1; s >>= 1) mc = fmaxf(mc, __shfl_xor(mc, s, 16));
      float mn = fmaxf(m[i], mc);
      sc[i] = __expf(m[i] - mn);
      float lsum = 0.f;
#pragma unroll
      for (int j = 0; j < 4; ++j) {
        float p = __expf(S[i][j] - mn);
        S[i][j] = p;
        lsum += p;
      }
#pragma unroll
      for (int s = 8; s >= 1; s >>= 1) lsum += __shfl_xor(lsum, s, 16);
      l[i] = l[i] * sc[i] + lsum;
      m[i] = mn;
#pragma unroll
      for (int j = 0; j < 4; ++j) Ps[ty * 4 + i][tx * 4 + j] = S[i][j];
    }
    if (tx == 0) {
#pragma unroll
      for (int i = 0; i < 4; ++i) mScale[ty * 4 + i] = sc[i];
    }
    __syncthreads();
#pragma unroll
    for (int cq = 0; cq < 4; ++cq) {
#pragma unroll
      for (int r = 0; r < 16; ++r) {
        int idx = tid + r * 256;
        int cpr = idx >> 6, j = idx & 63;
        Gs[cpr][j] = gb[(size_t)(cq * 64 + cpr) * TT + j0 + j];
      }
      __syncthreads();
      float scj[4];
#pragma unroll
      for (int jq = 0; jq < 4; ++jq) scj[jq] = mScale[tx * 4 + jq];
#pragma unroll
      for (int ci = 0; ci < 4; ++ci)
#pragma unroll
        for (int jq = 0; jq < 4; ++jq) acc[cq][ci][jq] *= scj[jq];
      for (int j = 0; j < 64; ++j) {
        float a[4], p[4];
#pragma unroll
        for (int ci = 0; ci < 4; ++ci) a[ci] = Gs[ty * 4 + ci][j];
#pragma unroll
        for (int jq = 0; jq < 4; ++jq) p[jq] = Ps[tx * 4 + jq][j];
#pragma unroll
        for (int ci = 0; ci < 4; ++ci)
#pragma unroll
          for (int jq = 0; jq < 4; ++jq) acc[cq][ci][jq] += a[ci] * p[jq];
      }
      __syncthreads();
    }
  }
  if (tx == 0) {
#pragma unroll
    for (int i = 0; i < 4; ++i) lArr[ty * 4 + i] = l[i];
  }
  __syncthreads();
  float linv[4];
#pragma unroll
  for (int jq = 0; jq < 4; ++jq) linv[jq] = 1.f / lArr[tx * 4 + jq];
#pragma unroll
  for (int cq = 0; cq < 4; ++cq)
#pragma unroll
    for (int ci = 0; ci < 4; ++ci)
#pragma unroll
      for (int jq = 0; jq < 4; ++jq)
        y[((size_t)b * ICC + cq * 64 + ty * 4 + ci) * TT + i0 + tx * 4 + jq] =
            acc[cq][ci][jq] * linv[jq];
}

// ---------------------------------------------------------------------------
extern "C" void kernel_launch(void* const* d_in, const int* in_sizes, int n_in,
                              void* d_out, int out_size, void* d_ws,
                              size_t ws_size, hipStream_t stream) {
  const float* x = (const float*)d_in[0];
  const float* g_w = (const float*)d_in[1];
  const float* g_b = (const float*)d_in[2];
  const float* th_w = (const float*)d_in[3];
  const float* th_b = (const float*)d_in[4];
  const float* ph_w = (const float*)d_in[5];
  const float* ph_b = (const float*)d_in[6];
  const float* W_w = (const float*)d_in[7];
  const float* W_b = (const float*)d_in[8];
  const float* gamma = (const float*)d_in[9];
  const float* beta = (const float*)d_in[10];
  float* out = (float*)d_out;
  dim3 blk(256);

  const size_t NP = (size_t)BB * TT * ICC;  // 4,194,304
  const size_t NW = 131072;                 // 256*512
  const size_t need = (8 * NP + 8 * NW) * sizeof(f16) + 8192 + 4096;

  if (ws_size >= need) {
    // ---------------- fast MFMA path ----------------
    f16* p = (f16*)d_ws;
    f16 *thH = p, *thL = thH + NP, *phH = thL + NP, *phL = phH + NP;
    f16 *gH = phL + NP, *gL = gH + NP, *yH = gL + NP, *yL = yH + NP;
    f16* wp = yL + NP;
    f16 *gwH = wp, *gwL = gwH + NW, *twH = gwL + NW, *twL = twH + NW;
    f16 *pwH = twL + NW, *pwL = pwH + NW, *wwH = pwL + NW, *wwL = wwH + NW;
    double* statd = (double*)(wwL + NW);
    float* meanb = (float*)(statd + 1024);
    float* rstdb = meanb + 512;
    f16* xTh = (f16*)d_out;  // xT hi/lo lives in d_out (dead before W-conv)
    f16* xTl = xTh + (size_t)BB * TT * CC;

    split_transpose_x<<<dim3(TT / 32, CC / 32, BB), dim3(32, 8), 0, stream>>>(
        x, xTh, xTl);
    split_w<<<512, 256, 0, stream>>>(g_w, gwH, gwL, (int)NW);
    split_w<<<512, 256, 0, stream>>>(th_w, twH, twL, (int)NW);
    split_w<<<512, 256, 0, stream>>>(ph_w, pwH, pwL, (int)NW);
    split_w<<<512, 256, 0, stream>>>(W_w, wwH, wwL, (int)NW);
    zero_stats<<<1, 1024, 0, stream>>>(statd);

    // theta/phi: D[t][ic] = xT * W^T   (M=T, N=IC, K=C, bias on N)
    gemm_nt<TT, ICC, CC, true, false><<<dim3(2, 16, BB), blk, 0, stream>>>(
        xTh, xTl, (long)TT * CC, twH, twL, 0, th_b, thH, thL, nullptr,
        (long)TT * ICC, nullptr, nullptr);
    gemm_nt<TT, ICC, CC, true, false><<<dim3(2, 16, BB), blk, 0, stream>>>(
        xTh, xTl, (long)TT * CC, pwH, pwL, 0, ph_b, phH, phL, nullptr,
        (long)TT * ICC, nullptr, nullptr);
    // g: D[ic][t] = Wg * xT^T   (M=IC, N=T, K=C, bias on M)
    gemm_nt<ICC, TT, CC, false, false><<<dim3(16, 2, BB), blk, 0, stream>>>(
        gwH, gwL, 0, xTh, xTl, (long)TT * CC, g_b, gH, gL, nullptr,
        (long)ICC * TT, nullptr, nullptr);
    // attention -> y [b][t][ic]
    attn_mfma<<<256, blk, 0, stream>>>(thH, thL, phH, phL, gH, gL, yH, yL);
    // W conv: D[o][t] -> d_out + BN stats  (M=C, N=T, K=IC, bias on M)
    gemm_nt<CC, TT, ICC, false, true><<<dim3(16, 4, BB), blk, 0, stream>>>(
        wwH, wwL, 0, yH, yL, (long)TT * ICC, W_b, nullptr, nullptr, out,
        (long)CC * TT, statd, statd + CC);
    bn_stats<<<1, 512, 0, stream>>>(statd, statd + CC, meanb, rstdb);
    bn_apply<<<2048, 256, 0, stream>>>(out, x, meanb, rstdb, gamma, beta);
  } else {
    // ---------------- fallback fp32 path ----------------
    float* ws = (float*)d_ws;
    const size_t np = (size_t)BB * ICC * TT;
    float* thb = ws;
    float* phb = ws + np;
    float* gbuf = ws + 2 * np;
    float* yb = thb;
    double* statd = (double*)(ws + 3 * np);
    float* meanb = (float*)(statd + 1024);
    float* rstdb = meanb + 512;
    gemm_proj<ICC, CC, false><<<dim3(TT / 64, ICC / 64, BB), blk, 0, stream>>>(
        th_w, th_b, x, thb, nullptr, nullptr);
    gemm_proj<ICC, CC, false><<<dim3(TT / 64, ICC / 64, BB), blk, 0, stream>>>(
        ph_w, ph_b, x, phb, nullptr, nullptr);
    gemm_proj<ICC, CC, false><<<dim3(TT / 64, ICC / 64, BB), blk, 0, stream>>>(
        g_w, g_b, x, gbuf, nullptr, nullptr);
    attn_flash<<<dim3(TT / 64, BB), blk, 0, stream>>>(thb, phb, gbuf, yb);
    zero_stats<<<1, 1024, 0, stream>>>(statd);
    gemm_proj<CC, ICC, true><<<dim3(TT / 64, CC / 64, BB), blk, 0, stream>>>(
        W_w, W_b, yb, out, statd, statd + CC);
    bn_stats<<<1, 512, 0, stream>>>(statd, statd + CC, meanb, rstdb);
    bn_apply<<<2048, 256, 0, stream>>>(out, x, meanb, rstdb, gamma, beta);
  }
}